// Round 9
// baseline (580.275 us; speedup 1.0000x reference)
//
#include <hip/hip_runtime.h>

typedef unsigned short u16;
typedef __attribute__((ext_vector_type(8))) short bf16x8;
typedef __attribute__((ext_vector_type(4))) float f32x4;

#define INV_SCALE 0.17677669529663687f

static __device__ __forceinline__ float b2f(u16 u) {
    union { unsigned int i; float f; } v; v.i = ((unsigned int)u) << 16; return v.f;
}
static __device__ __forceinline__ u16 f2b(float f) {
    union { float f; unsigned int i; } v; v.f = f;
    unsigned int r = (v.i + 0x7FFFu + ((v.i >> 16) & 1u)) >> 16;
    return (u16)r;
}

// ---- param arena segment table (bf16 elements), shared host/device ----
#define NSEG 23
__device__ __constant__ int d_seg_off[NSEG + 1] = {
    0, 8192, 270336, 272384, 272512, 273536, 273664, 273792, 322944, 372096,
    421248, 470400, 519552, 519936, 520320, 520704, 717312, 718848, 915456,
    915840, 916224, 916608, 916736, 916744};
static const int h_seg_off[NSEG + 1] = {
    0, 8192, 270336, 272384, 272512, 273536, 273664, 273792, 322944, 372096,
    421248, 470400, 519552, 519936, 520320, 520704, 717312, 718848, 915456,
    915840, 916224, 916608, 916736, 916744};
#define ARENA_TOTAL 916744

struct ParamPtrs { const void* p[NSEG]; };

// ---------------------------------------------------------------- param convert
__global__ __launch_bounds__(256) void convert_params(ParamPtrs pp, u16* __restrict__ arena) {
    const unsigned int probe = ((const unsigned int*)pp.p[13])[0];   // ln1_g[0] == 1.0
    const bool f32 = (probe == 0x3F800000u);
    for (int e = blockIdx.x * 256 + threadIdx.x; e < ARENA_TOTAL; e += gridDim.x * 256) {
        int k = 0;
        #pragma unroll
        for (int s2 = 1; s2 < NSEG; ++s2) if (e >= d_seg_off[s2]) k = s2;
        int local = e - d_seg_off[k];
        u16 v;
        if (k == 22 && local >= 1) v = 0;   // bout padded 1 -> 8
        else v = f32 ? f2b(((const float*)pp.p[k])[local]) : ((const u16*)pp.p[k])[local];
        arena[e] = v;
    }
}

// ---------------------------------------------------------------- mask dtype probe (tiny)
__global__ __launch_bounds__(256) void probe_kernel(const void* mask, int* __restrict__ mode) {
    __shared__ int f16, f32s, u8s;
    int tid = threadIdx.x;
    if (tid == 0) { f16 = 0; f32s = 0; u8s = 0; }
    __syncthreads();
    const u16* mu = (const u16*)mask;
    const unsigned int* mw = (const unsigned int*)mask;
    if (mu[2 * tid] == 0x3F80u) atomicOr(&f16, 1);
    if (mw[tid] == 0x3F800000u) atomicOr(&f32s, 1);
    if (mw[tid] > 1u) atomicOr(&u8s, 1);
    __syncthreads();
    if (tid == 0) mode[0] = f16 ? 0 : (f32s ? 3 : (u8s ? 1 : 2));
}

// ---------------------------------------------------------------- tok assembly (mask fused)
__global__ __launch_bounds__(256) void assemble_kernel(
    const u16* __restrict__ x, const u16* __restrict__ ea,
    const void* __restrict__ mask, const int* __restrict__ modeptr,
    const u16* __restrict__ nodeW, const u16* __restrict__ nodeB,
    const u16* __restrict__ edgeW, const u16* __restrict__ edgeB, const u16* __restrict__ noedge,
    float* __restrict__ tokf, u16* __restrict__ tokb)
{
    const int md = modeptr[0];
    int g = blockIdx.x * 256 + threadIdx.x;      // [0, 1048576)
    int t = g >> 5, dq = g & 31, d0 = dq * 4;
    int b = t >> 12, i = (t >> 6) & 63, j = t & 63;
    float v[4];
    if (i == j) {
        #pragma unroll
        for (int c = 0; c < 4; c++) v[c] = b2f(nodeB[d0 + c]);
        #pragma unroll
        for (int e = 0; e < 16; e++) {
            float xe = b2f(x[(b * 64 + i) * 16 + e]);
            #pragma unroll
            for (int c = 0; c < 4; c++) v[c] += xe * b2f(nodeW[e * 128 + d0 + c]);
        }
    } else {
        bool edge;
        if (md == 0)      edge = ((const u16*)mask)[t] != 0;
        else if (md == 3) edge = ((const float*)mask)[t] != 0.0f;
        else if (md == 1) edge = ((const unsigned char*)mask)[t] != 0;
        else              edge = ((const unsigned int*)mask)[t] != 0;
        if (edge) {
            #pragma unroll
            for (int c = 0; c < 4; c++) v[c] = b2f(edgeB[d0 + c]);
            #pragma unroll
            for (int e = 0; e < 8; e++) {
                float ae = b2f(ea[t * 8 + e]);
                #pragma unroll
                for (int c = 0; c < 4; c++) v[c] += ae * b2f(edgeW[e * 128 + d0 + c]);
            }
        } else {
            #pragma unroll
            for (int c = 0; c < 4; c++) v[c] = b2f(noedge[d0 + c]);
        }
    }
    *(float4*)(tokf + (size_t)t * 128 + d0) = make_float4(v[0], v[1], v[2], v[3]);
    u16 pk[4];
    #pragma unroll
    for (int c = 0; c < 4; c++) pk[c] = f2b(v[c]);
    *(uint2*)(tokb + (size_t)t * 128 + d0) = *(uint2*)pk;
}

// ---------------------------------------------------------------- generic GEMM
// modes: 1=bias+relu->bf16(outb), 2=bias+residual add into tokf, 3=qkv scatter
// mode 3: by==2 (v1) writes FP32 into tokf (= v1f buffer); others bf16.
// Epilogue: LDS transpose (XOR-swizzled) -> coalesced vector stores.
__global__ __launch_bounds__(256) void gemm_kernel(
    const u16* __restrict__ A, int lda,
    const u16* __restrict__ B0, const u16* __restrict__ B1,
    const u16* __restrict__ B2, const u16* __restrict__ B3,
    int ldb, const u16* __restrict__ bias,
    int K, int mode,
    u16* __restrict__ outb, int ldc,
    float* __restrict__ tokf,
    u16* __restrict__ qb, u16* __restrict__ kb, u16* __restrict__ v2b)
{
    __shared__ __align__(16) u16 smem[2 * 128 * 72];   // 36864 B
    u16* As = smem;
    u16* Bs = smem + 128 * 72;
    int tid = threadIdx.x;
    int m0 = blockIdx.x * 128;
    int by = blockIdx.y;
    const u16* Bp; int c0;
    if (mode == 3) { Bp = (by == 0) ? B0 : (by == 1) ? B1 : (by == 2) ? B2 : B3; c0 = 0; }
    else { Bp = B0; c0 = by * 128; }

    int w = tid >> 6, lane = tid & 63;
    int q = lane >> 4, r16 = lane & 15;
    int rw = (w >> 1) * 64, cw = (w & 1) * 64;

    f32x4 acc[4][4];
    #pragma unroll
    for (int mi = 0; mi < 4; mi++)
        #pragma unroll
        for (int ni = 0; ni < 4; ni++) acc[mi][ni] = (f32x4){0.f, 0.f, 0.f, 0.f};

    int nkt = K >> 6;
    for (int kt = 0; kt < nkt; ++kt) {
        int k0 = kt * 64;
        __syncthreads();
        #pragma unroll
        for (int it = 0; it < 4; ++it) {               // A: 128 x 64
            int idx = tid + it * 256;
            int row = idx >> 3, ch = idx & 7;
            uint4 d = *(const uint4*)(A + (size_t)(m0 + row) * lda + k0 + ch * 8);
            *(uint4*)&As[row * 72 + ch * 8] = d;
        }
        #pragma unroll
        for (int it = 0; it < 4; ++it) {               // B: 64 x 128 -> BT swizzled
            int idx = tid + it * 256;
            int kk = idx >> 4, nc = idx & 15;
            uint4 d = *(const uint4*)(Bp + (size_t)(k0 + kk) * ldb + c0 + nc * 8);
            const u16* ds = (const u16*)&d;
            int chunk = kk >> 3, kin = kk & 7;
            #pragma unroll
            for (int e = 0; e < 8; ++e) {
                int n = nc * 8 + e;
                int ch2 = chunk ^ ((n >> 3) & 7);
                Bs[n * 72 + ch2 * 8 + kin] = ds[e];
            }
        }
        __syncthreads();
        #pragma unroll
        for (int ks = 0; ks < 2; ++ks) {
            bf16x8 fa[4], fb[4];
            #pragma unroll
            for (int mi = 0; mi < 4; mi++)
                fa[mi] = *(const bf16x8*)&As[(rw + mi * 16 + r16) * 72 + ks * 32 + q * 8];
            #pragma unroll
            for (int ni = 0; ni < 4; ni++) {
                int n = cw + ni * 16 + r16;
                int ch2 = (ks * 4 + q) ^ ((n >> 3) & 7);
                fb[ni] = *(const bf16x8*)&Bs[n * 72 + ch2 * 8];
            }
            #pragma unroll
            for (int mi = 0; mi < 4; mi++)
                #pragma unroll
                for (int ni = 0; ni < 4; ni++)
                    acc[mi][ni] = __builtin_amdgcn_mfma_f32_16x16x32_bf16(fa[mi], fb[ni], acc[mi][ni], 0, 0, 0);
        }
    }

    // ---------------- epilogue: LDS transpose, coalesced stores ----------------
    int bl = m0 >> 12, it0 = (m0 >> 6) & 63;
    bool fp32path = (mode == 2) || (mode == 3 && by == 2);
    __syncthreads();
    if (!fp32path) {
        u16* cs = smem;                                // [128][128] u16, XOR-swizzled
        #pragma unroll
        for (int mi = 0; mi < 4; mi++) {
            #pragma unroll
            for (int ni = 0; ni < 4; ni++) {
                int col = cw + ni * 16 + r16;
                int ch = col >> 3, cl = col & 7;
                #pragma unroll
                for (int rr = 0; rr < 4; rr++) {
                    int r = rw + mi * 16 + q * 4 + rr;
                    float v = acc[mi][ni][rr];
                    if (mode == 1) { v += b2f(bias[c0 + col]); v = fmaxf(v, 0.f); }
                    cs[r * 128 + (((ch ^ (r & 15)) << 3) | cl)] = f2b(v);
                }
            }
        }
        __syncthreads();
        if (mode == 1) {
            #pragma unroll
            for (int it = 0; it < 8; ++it) {
                int idx = tid + it * 256;              // (r:7 | c8:4)
                int r = idx >> 4, c8 = idx & 15;
                uint4 d = *(const uint4*)&cs[r * 128 + ((c8 ^ (r & 15)) << 3)];
                *(uint4*)&outb[(size_t)(m0 + r) * ldc + c0 + c8 * 8] = d;
            }
        } else if (by == 0) {                          // q: [bh][l=jt][i=it][32]
            #pragma unroll
            for (int it = 0; it < 8; ++it) {
                int idx = tid + it * 256;              // (h:2 | jt:6 | itl:1 | d8:2)
                int h = idx >> 9, jt = (idx >> 3) & 63, itl = (idx >> 2) & 1, d8 = idx & 3;
                int r = itl * 64 + jt, c8 = h * 4 + d8;
                uint4 d = *(const uint4*)&cs[r * 128 + ((c8 ^ (r & 15)) << 3)];
                *(uint4*)&qb[((((size_t)(bl * 4 + h)) * 64 + jt) * 64 + it0 + itl) * 32 + d8 * 8] = d;
            }
        } else {                                       // k / v2: [bh][i=it][j=jt][32]
            u16* dp = (by == 1) ? kb : v2b;
            #pragma unroll
            for (int it = 0; it < 8; ++it) {
                int idx = tid + it * 256;              // (h:2 | itl:1 | jt:6 | d8:2)
                int h = idx >> 9, itl = (idx >> 8) & 1, jt = (idx >> 2) & 63, d8 = idx & 3;
                int r = itl * 64 + jt, c8 = h * 4 + d8;
                uint4 d = *(const uint4*)&cs[r * 128 + ((c8 ^ (r & 15)) << 3)];
                *(uint4*)&dp[((((size_t)(bl * 4 + h)) * 64 + it0 + itl) * 64 + jt) * 32 + d8 * 8] = d;
            }
        }
    } else {
        float* cf = (float*)smem;                      // [128][64] fp32, XOR-swizzled
        #pragma unroll
        for (int hp = 0; hp < 2; ++hp) {
            if (hp) __syncthreads();
            if ((cw >> 6) == hp) {                     // wave-uniform: this wave's cols in this half
                #pragma unroll
                for (int mi = 0; mi < 4; mi++) {
                    #pragma unroll
                    for (int ni = 0; ni < 4; ni++) {
                        int colh = (cw & 63) + ni * 16 + r16;
                        int ch4 = colh >> 2, cl = colh & 3;
                        #pragma unroll
                        for (int rr = 0; rr < 4; rr++) {
                            int r = rw + mi * 16 + q * 4 + rr;
                            cf[r * 64 + (((ch4 ^ (r & 15)) << 2) | cl)] = acc[mi][ni][rr];
                        }
                    }
                }
            }
            __syncthreads();
            if (mode == 2) {                           // residual RMW into tokf
                #pragma unroll
                for (int it = 0; it < 8; ++it) {
                    int idx = tid + it * 256;          // (r:7 | c4:4)
                    int r = idx >> 4, c4 = idx & 15;
                    f32x4 v = *(const f32x4*)&cf[r * 64 + ((c4 ^ (r & 15)) << 2)];
                    int col = hp * 64 + c4 * 4;
                    float* tp = tokf + (size_t)(m0 + r) * 128 + col;
                    f32x4 t = *(const f32x4*)tp;
                    #pragma unroll
                    for (int e = 0; e < 4; e++) t[e] += v[e] + b2f(bias[col + e]);
                    *(f32x4*)tp = t;
                }
            } else {                                   // v1f fp32: [bh][i=it][l=jt][32]
                #pragma unroll
                for (int it = 0; it < 8; ++it) {
                    int idx = tid + it * 256;          // (hh:1 | itl:1 | jt:6 | d4:3)
                    int hh = idx >> 10, itl = (idx >> 9) & 1, jt = (idx >> 3) & 63, d4 = idx & 7;
                    int r = itl * 64 + jt;
                    int colh = hh * 32 + d4 * 4;
                    f32x4 v = *(const f32x4*)&cf[r * 64 + (((colh >> 2) ^ (r & 15)) << 2)];
                    int h = hp * 2 + hh;
                    *(f32x4*)&tokf[((((size_t)(bl * 4 + h)) * 64 + it0 + itl) * 64 + jt) * 32 + d4 * 4] = v;
                }
            }
        }
    }
}

// ---------------------------------------------------------------- s = QK^T/scale (bf16 out)
__global__ __launch_bounds__(64) void attn_s_kernel(
    const u16* __restrict__ qb, const u16* __restrict__ kb, u16* __restrict__ s)
{
    __shared__ __align__(16) u16 qs[64 * 40];
    __shared__ __align__(16) u16 ks_[64 * 40];
    int g = blockIdx.x;
    int l = g & 63, bh = g >> 6;
    const u16* Q = qb + ((size_t)bh * 64 + l) * 2048;
    const u16* Kp = kb + ((size_t)bh * 64 + l) * 2048;
    int lane = threadIdx.x;
    #pragma unroll
    for (int it = 0; it < 4; ++it) {
        int idx = lane + it * 64;
        int row = idx >> 2, c4 = idx & 3;
        *(uint4*)&qs[row * 40 + c4 * 8] = *(const uint4*)(Q + row * 32 + c4 * 8);
        *(uint4*)&ks_[row * 40 + c4 * 8] = *(const uint4*)(Kp + row * 32 + c4 * 8);
    }
    __syncthreads();
    int q = lane >> 4, r16 = lane & 15;
    f32x4 acc[4][4];
    #pragma unroll
    for (int mi = 0; mi < 4; mi++)
        #pragma unroll
        for (int ni = 0; ni < 4; ni++) acc[mi][ni] = (f32x4){0.f, 0.f, 0.f, 0.f};
    bf16x8 fa[4], fb[4];
    #pragma unroll
    for (int mi = 0; mi < 4; mi++) fa[mi] = *(const bf16x8*)&qs[(mi * 16 + r16) * 40 + q * 8];
    #pragma unroll
    for (int ni = 0; ni < 4; ni++) fb[ni] = *(const bf16x8*)&ks_[(ni * 16 + r16) * 40 + q * 8];
    #pragma unroll
    for (int mi = 0; mi < 4; mi++)
        #pragma unroll
        for (int ni = 0; ni < 4; ni++)
            acc[mi][ni] = __builtin_amdgcn_mfma_f32_16x16x32_bf16(fa[mi], fb[ni], acc[mi][ni], 0, 0, 0);
    u16* sb = s + (size_t)bh * 262144 + l * 64;
    #pragma unroll
    for (int mi = 0; mi < 4; mi++)
        #pragma unroll
        for (int ni = 0; ni < 4; ni++)
            #pragma unroll
            for (int rr = 0; rr < 4; rr++) {
                int i = mi * 16 + q * 4 + rr, j = ni * 16 + r16;
                sb[(size_t)i * 4096 + j] = f2b(acc[mi][ni][rr] * INV_SCALE);
            }
}

// ---------------------------------------------------------------- softmax over l (bf16 in/out)
__global__ __launch_bounds__(256) void softmax_kernel(u16* __restrict__ s) {
    int g = blockIdx.x * 256 + threadIdx.x;
    int j = g & 63, bhi = g >> 6;
    u16* p = s + (size_t)bhi * 4096 + j;
    float r[64];
    float mx = -1e30f;
    #pragma unroll
    for (int l = 0; l < 64; l++) { r[l] = b2f(p[l * 64]); mx = fmaxf(mx, r[l]); }
    float sum = 0.f;
    #pragma unroll
    for (int l = 0; l < 64; l++) { r[l] = __expf(r[l] - mx); sum += r[l]; }
    float is = 1.0f / sum;
    #pragma unroll
    for (int l = 0; l < 64; l++) p[l * 64] = f2b(r[l] * is);
}

// ---------------------------------------------------------------- o = sum_l a*v1*v2
// block = (bh, 4-i-group), 256 threads (4 waves = 4 d-octants), grid (NB*4, 16) = 2 blocks/CU.
// v2 in LDS (stride-36 fp32, conflict-free); a via register-prefetched global ushort loads
// (VMEM port); v1 via wave-uniform global reads (scalar path). Inner loop LDS cost:
// 8 reads + 8 staging writes per chunk per wave (vs 56 in R8).
__global__ __launch_bounds__(256) void attn_o_kernel(
    const u16* __restrict__ a, const float* __restrict__ v1f, const u16* __restrict__ v2b,
    u16* __restrict__ ob)
{
    __shared__ __align__(16) float v2s[4 * 2304];     // 36864 B
    int bh = blockIdx.x;
    int i0 = blockIdx.y * 4;
    int bl = bh >> 2, h = bh & 3;
    int tid = threadIdx.x;
    int w = __builtin_amdgcn_readfirstlane(tid >> 6);  // 0..3 (d-octant)
    int j = tid & 63;
    int dh = w * 8;
    const u16*   v2base = v2b + (size_t)bh * 131072;
    const float* v1u    = v1f + (size_t)bh * 131072 + (size_t)i0 * 2048 + dh;  // uniform
    const u16*   abase  = a + (size_t)bh * 262144 + (size_t)i0 * 4096 + j;

    int lz[4], jz[4], cz[4];
    #pragma unroll
    for (int it = 0; it < 4; ++it) {
        int idx = tid + it * 256;            // (l:2 | j:6 | c4:2)
        lz[it] = idx >> 8; jz[it] = (idx >> 2) & 63; cz[it] = idx & 3;
    }

    uint4 pv2[4];
    u16 pac[16], pan[16];

#define LOADV2(l0_)                                                                  \
    _Pragma("unroll")                                                                \
    for (int it = 0; it < 4; ++it)                                                   \
        pv2[it] = *(const uint4*)(v2base + ((size_t)((l0_) + lz[it]) * 64 + jz[it]) * 32 + cz[it] * 8);

#define LOADA(l0_, dst)                                                              \
    _Pragma("unroll")                                                                \
    for (int ii = 0; ii < 4; ++ii)                                                   \
        _Pragma("unroll")                                                            \
        for (int lc = 0; lc < 4; ++lc)                                               \
            dst[ii * 4 + lc] = abase[(size_t)ii * 4096 + ((l0_) + lc) * 64];

#define STOREV2()                                                                    \
    _Pragma("unroll")                                                                \
    for (int it = 0; it < 4; ++it) {                                                 \
        const u16* ds = (const u16*)&pv2[it];                                        \
        float* dst = &v2s[lz[it] * 2304 + jz[it] * 36 + cz[it] * 8];                 \
        _Pragma("unroll")                                                            \
        for (int e = 0; e < 8; e++) dst[e] = b2f(ds[e]);                             \
    }

    float acc[4][8];
    #pragma unroll
    for (int i = 0; i < 4; i++)
        #pragma unroll
        for (int e = 0; e < 8; e++) acc[i][e] = 0.f;

    LOADV2(0);
    LOADA(0, pac);
    for (int ch = 0; ch < 16; ++ch) {
        if (ch) __syncthreads();             // previous chunk's readers done
        STOREV2();                           // uses current pv2
        if (ch + 1 < 16) { LOADV2((ch + 1) * 4); LOADA((ch + 1) * 4, pan); }
        __syncthreads();
        #pragma unroll
        for (int lc = 0; lc < 4; ++lc) {
            const float* vp = &v2s[lc * 2304 + j * 36 + dh];
            float v2r[8];
            *(f32x4*)&v2r[0] = *(const f32x4*)vp;
            *(f32x4*)&v2r[4] = *(const f32x4*)(vp + 4);
            #pragma unroll
            for (int ii = 0; ii < 4; ++ii) {
                float av = b2f(pac[ii * 4 + lc]);
                const float* v1p = v1u + ((size_t)ii * 64 + ch * 4 + lc) * 32;  // uniform
                #pragma unroll
                for (int e = 0; e < 8; e++)
                    acc[ii][e] += (av * v2r[e]) * v1p[e];
            }
        }
        #pragma unroll
        for (int t = 0; t < 16; ++t) pac[t] = pan[t];
    }
#undef LOADV2
#undef LOADA
#undef STOREV2

    #pragma unroll
    for (int ii = 0; ii < 4; ++ii) {
        u16 tmp[8];
        #pragma unroll
        for (int e = 0; e < 8; e++) tmp[e] = f2b(acc[ii][e]);
        *(uint4*)(ob + ((size_t)(bl * 64 + i0 + ii) * 64 + j) * 128 + h * 32 + dh) = *(uint4*)tmp;
    }
}

// ---------------------------------------------------------------- LayerNorm
__global__ __launch_bounds__(256) void ln_kernel(
    float* __restrict__ tokf, u16* __restrict__ tokb,
    const u16* __restrict__ g, const u16* __restrict__ bp)
{
    int row = blockIdx.x * 4 + (threadIdx.x >> 6);
    int lane = threadIdx.x & 63;
    float* p = tokf + (size_t)row * 128 + lane * 2;
    float x0 = p[0], x1 = p[1];
    float s = x0 + x1, sq = x0 * x0 + x1 * x1;
    #pragma unroll
    for (int off = 32; off; off >>= 1) { s += __shfl_xor(s, off, 64); sq += __shfl_xor(sq, off, 64); }
    float mean = s * (1.0f / 128.0f);
    float var = sq * (1.0f / 128.0f) - mean * mean;
    float rs = rsqrtf(var + 1e-5f);
    float y0 = (x0 - mean) * rs * b2f(g[lane * 2]) + b2f(bp[lane * 2]);
    float y1 = (x1 - mean) * rs * b2f(g[lane * 2 + 1]) + b2f(bp[lane * 2 + 1]);
    p[0] = y0; p[1] = y1;
    unsigned int pk = (unsigned int)f2b(y0) | ((unsigned int)f2b(y1) << 16);
    *(unsigned int*)(tokb + (size_t)row * 128 + lane * 2) = pk;
}

// ---------------------------------------------------------------- final diag head (fp32 out)
__global__ __launch_bounds__(256) void out_kernel(
    const float* __restrict__ tokf, const u16* __restrict__ Wout, const u16* __restrict__ bout,
    float* __restrict__ out)
{
    int g = blockIdx.x * 256 + threadIdx.x;   // [0,512)
    int b = g >> 6, i = g & 63;
    const float* p = tokf + ((size_t)(b * 64 + i) * 64 + i) * 128;
    float s = b2f(bout[0]);
    #pragma unroll
    for (int d = 0; d < 128; d++) s += p[d] * b2f(Wout[d]);
    out[g] = s;
}

// ---------------------------------------------------------------- launch
extern "C" void kernel_launch(void* const* d_in, const int* in_sizes, int n_in,
                              void* d_out, int out_size, void* d_ws, size_t ws_size,
                              hipStream_t stream) {
    const void* mask = d_in[2];
    ParamPtrs pp;
    for (int k = 0; k < NSEG; ++k) pp.p[k] = d_in[k < 2 ? k : k + 1];   // skip mask

    char* ws = (char*)d_ws;
    u16* arena = (u16*)ws;
    #define AP(k) ((const u16*)ws + h_seg_off[k])
    int*   mmode = (int*)(ws + 1835008);
    float* tokf  = (float*)(ws + 2097152);      // 16 MB
    u16*   tokb  = (u16*)(ws + 18874368);       //  8 MB
    const size_t base = 27262976;
    const size_t MB = 1048576ULL;

    // adaptive splits vs ws_size: attn needs base + 7*NB MB
    int NB = 8;
    while (NB > 1 && base + (size_t)NB * 7 * MB > ws_size) NB >>= 1;
    int F = 1;
    while (F < 8 && base + (size_t)(32768 / F) * 1024ULL > ws_size) F <<= 1;

    u16*   qb  = (u16*)(ws + base);                       // NB MB
    u16*   kb  = (u16*)(ws + base + (size_t)NB * MB);     // NB MB
    u16*   v2b = (u16*)(ws + base + (size_t)NB * 2 * MB); // NB MB
    float* v1f = (float*)(ws + base + (size_t)NB * 3 * MB); // 2*NB MB
    u16*   sb  = (u16*)(ws + base + (size_t)NB * 5 * MB);   // 2*NB MB
    u16*   ob  = qb;                              // q dead after attn_s
    u16*   ffb = qb;                              // attention bufs dead in FF phase

    convert_params<<<1024, 256, 0, stream>>>(pp, arena);
    probe_kernel<<<1, 256, 0, stream>>>(mask, mmode);
    assemble_kernel<<<4096, 256, 0, stream>>>(AP(0), AP(1), mask, mmode,
                                              AP(2), AP(3), AP(4), AP(5), AP(6), tokf, tokb);

    for (int l = 0; l < 3; ++l) {
        const u16* Wq_l  = AP(7)  + l * 16384;
        const u16* Wk_l  = AP(8)  + l * 16384;
        const u16* Wv1_l = AP(9)  + l * 16384;
        const u16* Wv2_l = AP(10) + l * 16384;
        const u16* Wo_l  = AP(11) + l * 16384;
        const u16* bo_l  = AP(12) + l * 128;
        const u16* g1_l  = AP(13) + l * 128;
        const u16* be1_l = AP(14) + l * 128;
        const u16* W1_l  = AP(15) + l * 65536;
        const u16* b1_l  = AP(16) + l * 512;
        const u16* W2_l  = AP(17) + l * 65536;
        const u16* b2_l  = AP(18) + l * 128;
        const u16* g2_l  = AP(19) + l * 128;
        const u16* be2_l = AP(20) + l * 128;

        for (int r = 0; r < 8 / NB; ++r) {
            size_t rowOff = (size_t)r * NB * 4096;
            gemm_kernel<<<dim3(NB * 32, 4), 256, 0, stream>>>(
                tokb + rowOff * 128, 128, Wq_l, Wk_l, Wv1_l, Wv2_l,
                128, (const u16*)0, 128, 3, (u16*)0, 0, v1f, qb, kb, v2b);
            attn_s_kernel<<<NB * 256, 64, 0, stream>>>(qb, kb, sb);
            softmax_kernel<<<NB * 64, 256, 0, stream>>>(sb);
            attn_o_kernel<<<dim3(NB * 4, 16), 256, 0, stream>>>(sb, v1f, v2b, ob);
            gemm_kernel<<<dim3(NB * 32, 1), 256, 0, stream>>>(
                ob, 128, Wo_l, (const u16*)0, (const u16*)0, (const u16*)0,
                128, bo_l, 128, 2, (u16*)0, 0, tokf + rowOff * 128,
                (u16*)0, (u16*)0, (u16*)0);
        }
        ln_kernel<<<8192, 256, 0, stream>>>(tokf, tokb, g1_l, be1_l);
        for (int f = 0; f < F; ++f) {
            size_t r0 = (size_t)f * (32768 / F);
            int RB = (32768 / F) / 128;
            gemm_kernel<<<dim3(RB, 4), 256, 0, stream>>>(
                tokb + r0 * 128, 128, W1_l, (const u16*)0, (const u16*)0, (const u16*)0,
                512, b1_l, 128, 1, ffb, 512, (float*)0, (u16*)0, (u16*)0, (u16*)0);
            gemm_kernel<<<dim3(RB, 1), 256, 0, stream>>>(
                ffb, 512, W2_l, (const u16*)0, (const u16*)0, (const u16*)0,
                128, b2_l, 512, 2, (u16*)0, 0, tokf + r0 * 128,
                (u16*)0, (u16*)0, (u16*)0);
        }
        ln_kernel<<<8192, 256, 0, stream>>>(tokf, tokb, g2_l, be2_l);
    }
    out_kernel<<<2, 256, 0, stream>>>(tokf, AP(21), AP(22), (float*)d_out);
}

// Round 10
// 579.225 us; speedup vs baseline: 1.0018x; 1.0018x over previous
//
#include <hip/hip_runtime.h>

typedef unsigned short u16;
typedef __attribute__((ext_vector_type(8))) short bf16x8;
typedef __attribute__((ext_vector_type(4))) float f32x4;

#define INV_SCALE 0.17677669529663687f

static __device__ __forceinline__ float b2f(u16 u) {
    union { unsigned int i; float f; } v; v.i = ((unsigned int)u) << 16; return v.f;
}
static __device__ __forceinline__ u16 f2b(float f) {
    union { float f; unsigned int i; } v; v.f = f;
    unsigned int r = (v.i + 0x7FFFu + ((v.i >> 16) & 1u)) >> 16;
    return (u16)r;
}

// ---- param arena segment table (bf16 elements), shared host/device ----
#define NSEG 23
__device__ __constant__ int d_seg_off[NSEG + 1] = {
    0, 8192, 270336, 272384, 272512, 273536, 273664, 273792, 322944, 372096,
    421248, 470400, 519552, 519936, 520320, 520704, 717312, 718848, 915456,
    915840, 916224, 916608, 916736, 916744};
static const int h_seg_off[NSEG + 1] = {
    0, 8192, 270336, 272384, 272512, 273536, 273664, 273792, 322944, 372096,
    421248, 470400, 519552, 519936, 520320, 520704, 717312, 718848, 915456,
    915840, 916224, 916608, 916736, 916744};
#define ARENA_TOTAL 916744
#define NTILE 78           // pre-swizzled weight tiles (64x128 each, 8192 u16)

struct ParamPtrs { const void* p[NSEG]; };

// ---------------------------------------------------------------- param convert
__global__ __launch_bounds__(256) void convert_params(ParamPtrs pp, u16* __restrict__ arena) {
    const unsigned int probe = ((const unsigned int*)pp.p[13])[0];   // ln1_g[0] == 1.0
    const bool f32 = (probe == 0x3F800000u);
    for (int e = blockIdx.x * 256 + threadIdx.x; e < ARENA_TOTAL; e += gridDim.x * 256) {
        int k = 0;
        #pragma unroll
        for (int s2 = 1; s2 < NSEG; ++s2) if (e >= d_seg_off[s2]) k = s2;
        int local = e - d_seg_off[k];
        u16 v;
        if (k == 22 && local >= 1) v = 0;   // bout padded 1 -> 8
        else v = f32 ? f2b(((const float*)pp.p[k])[local]) : ((const u16*)pp.p[k])[local];
        arena[e] = v;
    }
}

// ---------------------------------------------------------------- weight pre-swizzle
// Tile order: [l][mat5][kt2] (30) | W1 [l][cb4][kt2] (24) | W2 [l][kt8] (24).
// In-tile layout = exact MFMA B-fragment order: idx = ((((cwh*4+ni)*2+ks)*64+lane)*8+el.
__global__ __launch_bounds__(256) void prep_weights(const u16* __restrict__ arena, u16* __restrict__ wsw) {
    int e = blockIdx.x * 256 + threadIdx.x;          // < 78*8192
    int tile = e >> 13, r = e & 8191;
    int el = r & 7, lane = (r >> 3) & 63, ks = (r >> 9) & 1, ni = (r >> 10) & 3, cwh = (r >> 12) & 1;
    int nloc = cwh * 64 + ni * 16 + (lane & 15);
    int kloc = ks * 32 + (lane >> 4) * 8 + el;
    int moff, ldb, k0, c0;
    if (tile < 30) {
        int l = tile / 10, m5 = (tile % 10) / 2, kt = tile & 1;
        moff = d_seg_off[7 + m5] + l * 16384; ldb = 128; k0 = kt * 64; c0 = 0;
    } else if (tile < 54) {
        int t2 = tile - 30; int l = t2 / 8, cb = (t2 % 8) / 2, kt = t2 & 1;
        moff = d_seg_off[15] + l * 65536; ldb = 512; k0 = kt * 64; c0 = cb * 128;
    } else {
        int t3 = tile - 54; int l = t3 / 8, kt = t3 & 7;
        moff = d_seg_off[17] + l * 65536; ldb = 128; k0 = kt * 64; c0 = 0;
    }
    wsw[e] = arena[moff + (size_t)(k0 + kloc) * ldb + c0 + nloc];
}

// ---------------------------------------------------------------- mask dtype probe (tiny)
__global__ __launch_bounds__(256) void probe_kernel(const void* mask, int* __restrict__ mode) {
    __shared__ int f16, f32s, u8s;
    int tid = threadIdx.x;
    if (tid == 0) { f16 = 0; f32s = 0; u8s = 0; }
    __syncthreads();
    const u16* mu = (const u16*)mask;
    const unsigned int* mw = (const unsigned int*)mask;
    if (mu[2 * tid] == 0x3F80u) atomicOr(&f16, 1);
    if (mw[tid] == 0x3F800000u) atomicOr(&f32s, 1);
    if (mw[tid] > 1u) atomicOr(&u8s, 1);
    __syncthreads();
    if (tid == 0) mode[0] = f16 ? 0 : (f32s ? 3 : (u8s ? 1 : 2));
}

// ---------------------------------------------------------------- tok assembly (mask fused)
__global__ __launch_bounds__(256) void assemble_kernel(
    const u16* __restrict__ x, const u16* __restrict__ ea,
    const void* __restrict__ mask, const int* __restrict__ modeptr,
    const u16* __restrict__ nodeW, const u16* __restrict__ nodeB,
    const u16* __restrict__ edgeW, const u16* __restrict__ edgeB, const u16* __restrict__ noedge,
    float* __restrict__ tokf, u16* __restrict__ tokb)
{
    const int md = modeptr[0];
    int g = blockIdx.x * 256 + threadIdx.x;      // [0, 1048576)
    int t = g >> 5, dq = g & 31, d0 = dq * 4;
    int b = t >> 12, i = (t >> 6) & 63, j = t & 63;
    float v[4];
    if (i == j) {
        #pragma unroll
        for (int c = 0; c < 4; c++) v[c] = b2f(nodeB[d0 + c]);
        #pragma unroll
        for (int e = 0; e < 16; e++) {
            float xe = b2f(x[(b * 64 + i) * 16 + e]);
            #pragma unroll
            for (int c = 0; c < 4; c++) v[c] += xe * b2f(nodeW[e * 128 + d0 + c]);
        }
    } else {
        bool edge;
        if (md == 0)      edge = ((const u16*)mask)[t] != 0;
        else if (md == 3) edge = ((const float*)mask)[t] != 0.0f;
        else if (md == 1) edge = ((const unsigned char*)mask)[t] != 0;
        else              edge = ((const unsigned int*)mask)[t] != 0;
        if (edge) {
            #pragma unroll
            for (int c = 0; c < 4; c++) v[c] = b2f(edgeB[d0 + c]);
            #pragma unroll
            for (int e = 0; e < 8; e++) {
                float ae = b2f(ea[t * 8 + e]);
                #pragma unroll
                for (int c = 0; c < 4; c++) v[c] += ae * b2f(edgeW[e * 128 + d0 + c]);
            }
        } else {
            #pragma unroll
            for (int c = 0; c < 4; c++) v[c] = b2f(noedge[d0 + c]);
        }
    }
    *(float4*)(tokf + (size_t)t * 128 + d0) = make_float4(v[0], v[1], v[2], v[3]);
    u16 pk[4];
    #pragma unroll
    for (int c = 0; c < 4; c++) pk[c] = f2b(v[c]);
    *(uint2*)(tokb + (size_t)t * 128 + d0) = *(uint2*)pk;
}

// ---------------------------------------------------------------- GEMM (modes 1,3)
// B is PRE-SWIZZLED (fragment-ordered tiles): staging = linear b128 copy.
// mode 1: bias+relu -> bf16 outb (ldc).  mode 3: qkv scatter, by==2 (v1) -> fp32 v1f.
__global__ __launch_bounds__(256) void gemm_kernel(
    const u16* __restrict__ A, int lda,
    const u16* __restrict__ B0, const u16* __restrict__ B1,
    const u16* __restrict__ B2, const u16* __restrict__ B3,
    const u16* __restrict__ bias, int K, int mode,
    u16* __restrict__ outb, int ldc, float* __restrict__ v1f,
    u16* __restrict__ qb, u16* __restrict__ kb, u16* __restrict__ v2b)
{
    __shared__ __align__(16) u16 smem[17408];          // 34816 B: As 9216 + Bs 8192
    u16* As = smem;
    u16* Bs = smem + 9216;
    int tid = threadIdx.x;
    int m0 = blockIdx.x * 128;
    int by = blockIdx.y;
    const u16* Bp; int cblk;
    if (mode == 3) { Bp = (by == 0) ? B0 : (by == 1) ? B1 : (by == 2) ? B2 : B3; cblk = 0; }
    else { Bp = B0; cblk = by; }
    int c0 = (mode == 1) ? by * 128 : 0;

    int w = tid >> 6, lane = tid & 63;
    int q = lane >> 4, r16 = lane & 15;
    int rw = (w >> 1) * 64, cw = (w & 1) * 64, cwh = w & 1;

    f32x4 acc[4][4];
    #pragma unroll
    for (int mi = 0; mi < 4; mi++)
        #pragma unroll
        for (int ni = 0; ni < 4; ni++) acc[mi][ni] = (f32x4){0.f, 0.f, 0.f, 0.f};

    int nkt = K >> 6;
    for (int kt = 0; kt < nkt; ++kt) {
        int k0 = kt * 64;
        const u16* Bt = Bp + ((size_t)(cblk * nkt + kt)) * 8192;
        __syncthreads();
        #pragma unroll
        for (int it = 0; it < 4; ++it) {               // A: 128 x 64
            int idx = tid + it * 256;
            int row = idx >> 3, ch = idx & 7;
            uint4 d = *(const uint4*)(A + (size_t)(m0 + row) * lda + k0 + ch * 8);
            *(uint4*)&As[row * 72 + ch * 8] = d;
        }
        #pragma unroll
        for (int it = 0; it < 4; ++it) {               // B: linear fragment-ordered copy
            int idx = tid + it * 256;
            *(uint4*)&Bs[idx * 8] = *(const uint4*)(Bt + idx * 8);
        }
        __syncthreads();
        #pragma unroll
        for (int ks = 0; ks < 2; ++ks) {
            bf16x8 fa[4], fb[4];
            #pragma unroll
            for (int mi = 0; mi < 4; mi++)
                fa[mi] = *(const bf16x8*)&As[(rw + mi * 16 + r16) * 72 + ks * 32 + q * 8];
            #pragma unroll
            for (int ni = 0; ni < 4; ni++)
                fb[ni] = *(const bf16x8*)&Bs[(((cwh * 4 + ni) * 2 + ks) * 64 + lane) * 8];
            #pragma unroll
            for (int mi = 0; mi < 4; mi++)
                #pragma unroll
                for (int ni = 0; ni < 4; ni++)
                    acc[mi][ni] = __builtin_amdgcn_mfma_f32_16x16x32_bf16(fa[mi], fb[ni], acc[mi][ni], 0, 0, 0);
        }
    }

    // ---------------- epilogue: LDS transpose, coalesced stores ----------------
    int bl = m0 >> 12, it0 = (m0 >> 6) & 63;
    bool fp32path = (mode == 3 && by == 2);
    __syncthreads();
    if (!fp32path) {
        u16* cs = smem;                                // [128][128] u16, XOR-swizzled
        #pragma unroll
        for (int mi = 0; mi < 4; mi++) {
            #pragma unroll
            for (int ni = 0; ni < 4; ni++) {
                int col = cw + ni * 16 + r16;
                int ch = col >> 3, cl = col & 7;
                #pragma unroll
                for (int rr = 0; rr < 4; rr++) {
                    int r = rw + mi * 16 + q * 4 + rr;
                    float v = acc[mi][ni][rr];
                    if (mode == 1) { v += b2f(bias[c0 + col]); v = fmaxf(v, 0.f); }
                    cs[r * 128 + (((ch ^ (r & 15)) << 3) | cl)] = f2b(v);
                }
            }
        }
        __syncthreads();
        if (mode == 1) {
            #pragma unroll
            for (int it = 0; it < 8; ++it) {
                int idx = tid + it * 256;              // (r:7 | c8:4)
                int r = idx >> 4, c8 = idx & 15;
                uint4 d = *(const uint4*)&cs[r * 128 + ((c8 ^ (r & 15)) << 3)];
                *(uint4*)&outb[(size_t)(m0 + r) * ldc + c0 + c8 * 8] = d;
            }
        } else if (by == 0) {                          // q: [bh][l=jt][i=it][32]
            #pragma unroll
            for (int it = 0; it < 8; ++it) {
                int idx = tid + it * 256;              // (h:2 | jt:6 | itl:1 | d8:2)
                int h = idx >> 9, jt = (idx >> 3) & 63, itl = (idx >> 2) & 1, d8 = idx & 3;
                int r = itl * 64 + jt, c8 = h * 4 + d8;
                uint4 d = *(const uint4*)&cs[r * 128 + ((c8 ^ (r & 15)) << 3)];
                *(uint4*)&qb[((((size_t)(bl * 4 + h)) * 64 + jt) * 64 + it0 + itl) * 32 + d8 * 8] = d;
            }
        } else {                                       // k / v2: [bh][i=it][j=jt][32]
            u16* dp = (by == 1) ? kb : v2b;
            #pragma unroll
            for (int it = 0; it < 8; ++it) {
                int idx = tid + it * 256;              // (h:2 | itl:1 | jt:6 | d8:2)
                int h = idx >> 9, itl = (idx >> 8) & 1, jt = (idx >> 2) & 63, d8 = idx & 3;
                int r = itl * 64 + jt, c8 = h * 4 + d8;
                uint4 d = *(const uint4*)&cs[r * 128 + ((c8 ^ (r & 15)) << 3)];
                *(uint4*)&dp[((((size_t)(bl * 4 + h)) * 64 + it0 + itl) * 64 + jt) * 32 + d8 * 8] = d;
            }
        }
    } else {
        float* cf = (float*)smem;                      // [128][64] fp32, XOR-swizzled
        #pragma unroll
        for (int hp = 0; hp < 2; ++hp) {
            if (hp) __syncthreads();
            if (cwh == hp) {                           // wave-uniform
                #pragma unroll
                for (int mi = 0; mi < 4; mi++) {
                    #pragma unroll
                    for (int ni = 0; ni < 4; ni++) {
                        int colh = ni * 16 + r16;
                        int ch4 = colh >> 2, cl = colh & 3;
                        #pragma unroll
                        for (int rr = 0; rr < 4; rr++) {
                            int r = rw + mi * 16 + q * 4 + rr;
                            cf[r * 64 + (((ch4 ^ (r & 15)) << 2) | cl)] = acc[mi][ni][rr];
                        }
                    }
                }
            }
            __syncthreads();
            #pragma unroll
            for (int it = 0; it < 8; ++it) {           // v1f fp32: [bh][i=it][l=jt][32]
                int idx = tid + it * 256;              // (hh:1 | itl:1 | jt:6 | d4:3)
                int hh = idx >> 10, itl = (idx >> 9) & 1, jt = (idx >> 3) & 63, d4 = idx & 7;
                int r = itl * 64 + jt;
                int colh = hh * 32 + d4 * 4;
                f32x4 v = *(const f32x4*)&cf[r * 64 + (((colh >> 2) ^ (r & 15)) << 2)];
                int h = hp * 2 + hh;
                *(f32x4*)&v1f[((((size_t)(bl * 4 + h)) * 64 + it0 + itl) * 64 + jt) * 32 + d4 * 4] = v;
            }
        }
    }
}

// ---------------------------------------------------------------- GEMM + residual + LayerNorm
// Full 128-col output per block -> row stats computable in-block.
__global__ __launch_bounds__(256) void gemm_ln_kernel(
    const u16* __restrict__ A, int lda, const u16* __restrict__ Bsw, int K,
    const u16* __restrict__ bias, const u16* __restrict__ g, const u16* __restrict__ bb,
    float* __restrict__ tokf, u16* __restrict__ tokb)
{
    __shared__ __align__(16) float smemf[128 * 132];   // 67584 B
    u16* As = (u16*)smemf;
    u16* Bs = (u16*)smemf + 9216;
    int tid = threadIdx.x;
    int m0 = blockIdx.x * 128;
    int w = tid >> 6, lane = tid & 63;
    int q = lane >> 4, r16 = lane & 15;
    int rw = (w >> 1) * 64, cw = (w & 1) * 64, cwh = w & 1;

    f32x4 acc[4][4];
    #pragma unroll
    for (int mi = 0; mi < 4; mi++)
        #pragma unroll
        for (int ni = 0; ni < 4; ni++) acc[mi][ni] = (f32x4){0.f, 0.f, 0.f, 0.f};

    int nkt = K >> 6;
    for (int kt = 0; kt < nkt; ++kt) {
        int k0 = kt * 64;
        const u16* Bt = Bsw + (size_t)kt * 8192;
        __syncthreads();
        #pragma unroll
        for (int it = 0; it < 4; ++it) {
            int idx = tid + it * 256;
            int row = idx >> 3, ch = idx & 7;
            uint4 d = *(const uint4*)(A + (size_t)(m0 + row) * lda + k0 + ch * 8);
            *(uint4*)&As[row * 72 + ch * 8] = d;
        }
        #pragma unroll
        for (int it = 0; it < 4; ++it) {
            int idx = tid + it * 256;
            *(uint4*)&Bs[idx * 8] = *(const uint4*)(Bt + idx * 8);
        }
        __syncthreads();
        #pragma unroll
        for (int ks = 0; ks < 2; ++ks) {
            bf16x8 fa[4], fb[4];
            #pragma unroll
            for (int mi = 0; mi < 4; mi++)
                fa[mi] = *(const bf16x8*)&As[(rw + mi * 16 + r16) * 72 + ks * 32 + q * 8];
            #pragma unroll
            for (int ni = 0; ni < 4; ni++)
                fb[ni] = *(const bf16x8*)&Bs[(((cwh * 4 + ni) * 2 + ks) * 64 + lane) * 8];
            #pragma unroll
            for (int mi = 0; mi < 4; mi++)
                #pragma unroll
                for (int ni = 0; ni < 4; ni++)
                    acc[mi][ni] = __builtin_amdgcn_mfma_f32_16x16x32_bf16(fa[mi], fb[ni], acc[mi][ni], 0, 0, 0);
        }
    }

    // epilogue: scatter acc+bias into [128][132] fp32, then residual + LN per row
    __syncthreads();
    float* cf = smemf;
    #pragma unroll
    for (int mi = 0; mi < 4; mi++) {
        #pragma unroll
        for (int ni = 0; ni < 4; ni++) {
            int col = cw + ni * 16 + r16;
            float bv = b2f(bias[col]);
            #pragma unroll
            for (int rr = 0; rr < 4; rr++) {
                int r = rw + mi * 16 + q * 4 + rr;
                cf[r * 132 + col] = acc[mi][ni][rr] + bv;
            }
        }
    }
    __syncthreads();
    float g0 = b2f(g[lane * 2]), g1 = b2f(g[lane * 2 + 1]);
    float e0 = b2f(bb[lane * 2]), e1 = b2f(bb[lane * 2 + 1]);
    for (int itr = 0; itr < 32; ++itr) {
        int ro = itr * 4 + w;
        float* tp = tokf + (size_t)(m0 + ro) * 128 + lane * 2;
        float x0 = cf[ro * 132 + lane * 2] + tp[0];
        float x1 = cf[ro * 132 + lane * 2 + 1] + tp[1];
        float s = x0 + x1, sq = x0 * x0 + x1 * x1;
        #pragma unroll
        for (int off = 32; off; off >>= 1) { s += __shfl_xor(s, off, 64); sq += __shfl_xor(sq, off, 64); }
        float mean = s * (1.0f / 128.0f);
        float var = sq * (1.0f / 128.0f) - mean * mean;
        float rs = rsqrtf(var + 1e-5f);
        float y0 = (x0 - mean) * rs * g0 + e0;
        float y1 = (x1 - mean) * rs * g1 + e1;
        tp[0] = y0; tp[1] = y1;
        unsigned int pk = (unsigned int)f2b(y0) | ((unsigned int)f2b(y1) << 16);
        *(unsigned int*)(tokb + (size_t)(m0 + ro) * 128 + lane * 2) = pk;
    }
}

// ---------------------------------------------------------------- s = QK^T/scale (bf16 out)
__global__ __launch_bounds__(64) void attn_s_kernel(
    const u16* __restrict__ qb, const u16* __restrict__ kb, u16* __restrict__ s)
{
    __shared__ __align__(16) u16 qs[64 * 40];
    __shared__ __align__(16) u16 ks_[64 * 40];
    int g = blockIdx.x;
    int l = g & 63, bh = g >> 6;
    const u16* Q = qb + ((size_t)bh * 64 + l) * 2048;
    const u16* Kp = kb + ((size_t)bh * 64 + l) * 2048;
    int lane = threadIdx.x;
    #pragma unroll
    for (int it = 0; it < 4; ++it) {
        int idx = lane + it * 64;
        int row = idx >> 2, c4 = idx & 3;
        *(uint4*)&qs[row * 40 + c4 * 8] = *(const uint4*)(Q + row * 32 + c4 * 8);
        *(uint4*)&ks_[row * 40 + c4 * 8] = *(const uint4*)(Kp + row * 32 + c4 * 8);
    }
    __syncthreads();
    int q = lane >> 4, r16 = lane & 15;
    f32x4 acc[4][4];
    #pragma unroll
    for (int mi = 0; mi < 4; mi++)
        #pragma unroll
        for (int ni = 0; ni < 4; ni++) acc[mi][ni] = (f32x4){0.f, 0.f, 0.f, 0.f};
    bf16x8 fa[4], fb[4];
    #pragma unroll
    for (int mi = 0; mi < 4; mi++) fa[mi] = *(const bf16x8*)&qs[(mi * 16 + r16) * 40 + q * 8];
    #pragma unroll
    for (int ni = 0; ni < 4; ni++) fb[ni] = *(const bf16x8*)&ks_[(ni * 16 + r16) * 40 + q * 8];
    #pragma unroll
    for (int mi = 0; mi < 4; mi++)
        #pragma unroll
        for (int ni = 0; ni < 4; ni++)
            acc[mi][ni] = __builtin_amdgcn_mfma_f32_16x16x32_bf16(fa[mi], fb[ni], acc[mi][ni], 0, 0, 0);
    u16* sb = s + (size_t)bh * 262144 + l * 64;
    #pragma unroll
    for (int mi = 0; mi < 4; mi++)
        #pragma unroll
        for (int ni = 0; ni < 4; ni++)
            #pragma unroll
            for (int rr = 0; rr < 4; rr++) {
                int i = mi * 16 + q * 4 + rr, j = ni * 16 + r16;
                sb[(size_t)i * 4096 + j] = f2b(acc[mi][ni][rr] * INV_SCALE);
            }
}

// ---------------------------------------------------------------- softmax over l (bf16 in/out)
__global__ __launch_bounds__(256) void softmax_kernel(u16* __restrict__ s) {
    int g = blockIdx.x * 256 + threadIdx.x;
    int j = g & 63, bhi = g >> 6;
    u16* p = s + (size_t)bhi * 4096 + j;
    float r[64];
    float mx = -1e30f;
    #pragma unroll
    for (int l = 0; l < 64; l++) { r[l] = b2f(p[l * 64]); mx = fmaxf(mx, r[l]); }
    float sum = 0.f;
    #pragma unroll
    for (int l = 0; l < 64; l++) { r[l] = __expf(r[l] - mx); sum += r[l]; }
    float is = 1.0f / sum;
    #pragma unroll
    for (int l = 0; l < 64; l++) p[l * 64] = f2b(r[l] * is);
}

// ---------------------------------------------------------------- o = sum_l a*v1*v2
__global__ __launch_bounds__(256) void attn_o_kernel(
    const u16* __restrict__ a, const float* __restrict__ v1f, const u16* __restrict__ v2b,
    u16* __restrict__ ob)
{
    __shared__ __align__(16) float v2s[4 * 2304];     // 36864 B
    int bh = blockIdx.x;
    int i0 = blockIdx.y * 4;
    int bl = bh >> 2, h = bh & 3;
    int tid = threadIdx.x;
    int w = __builtin_amdgcn_readfirstlane(tid >> 6);  // 0..3 (d-octant)
    int j = tid & 63;
    int dh = w * 8;
    const u16*   v2base = v2b + (size_t)bh * 131072;
    const float* v1u    = v1f + (size_t)bh * 131072 + (size_t)i0 * 2048 + dh;  // uniform
    const u16*   abase  = a + (size_t)bh * 262144 + (size_t)i0 * 4096 + j;

    int lz[4], jz[4], cz[4];
    #pragma unroll
    for (int it = 0; it < 4; ++it) {
        int idx = tid + it * 256;            // (l:2 | j:6 | c4:2)
        lz[it] = idx >> 8; jz[it] = (idx >> 2) & 63; cz[it] = idx & 3;
    }

    uint4 pv2[4];
    u16 pac[16], pan[16];

#define LOADV2(l0_)                                                                  \
    _Pragma("unroll")                                                                \
    for (int it = 0; it < 4; ++it)                                                   \
        pv2[it] = *(const uint4*)(v2base + ((size_t)((l0_) + lz[it]) * 64 + jz[it]) * 32 + cz[it] * 8);

#define LOADA(l0_, dst)                                                              \
    _Pragma("unroll")                                                                \
    for (int ii = 0; ii < 4; ++ii)                                                   \
        _Pragma("unroll")                                                            \
        for (int lc = 0; lc < 4; ++lc)                                               \
            dst[ii * 4 + lc] = abase[(size_t)ii * 4096 + ((l0_) + lc) * 64];

#define STOREV2()                                                                    \
    _Pragma("unroll")                                                                \
    for (int it = 0; it < 4; ++it) {                                                 \
        const u16* ds = (const u16*)&pv2[it];                                        \
        float* dst = &v2s[lz[it] * 2304 + jz[it] * 36 + cz[it] * 8];                 \
        _Pragma("unroll")                                                            \
        for (int e = 0; e < 8; e++) dst[e] = b2f(ds[e]);                             \
    }

    float acc[4][8];
    #pragma unroll
    for (int i = 0; i < 4; i++)
        #pragma unroll
        for (int e = 0; e < 8; e++) acc[i][e] = 0.f;

    LOADV2(0);
    LOADA(0, pac);
    for (int ch = 0; ch < 16; ++ch) {
        if (ch) __syncthreads();
        STOREV2();
        if (ch + 1 < 16) { LOADV2((ch + 1) * 4); LOADA((ch + 1) * 4, pan); }
        __syncthreads();
        #pragma unroll
        for (int lc = 0; lc < 4; ++lc) {
            const float* vp = &v2s[lc * 2304 + j * 36 + dh];
            float v2r[8];
            *(f32x4*)&v2r[0] = *(const f32x4*)vp;
            *(f32x4*)&v2r[4] = *(const f32x4*)(vp + 4);
            #pragma unroll
            for (int ii = 0; ii < 4; ++ii) {
                float av = b2f(pac[ii * 4 + lc]);
                const float* v1p = v1u + ((size_t)ii * 64 + ch * 4 + lc) * 32;
                #pragma unroll
                for (int e = 0; e < 8; e++)
                    acc[ii][e] += (av * v2r[e]) * v1p[e];
            }
        }
        #pragma unroll
        for (int t = 0; t < 16; ++t) pac[t] = pan[t];
    }
#undef LOADV2
#undef LOADA
#undef STOREV2

    #pragma unroll
    for (int ii = 0; ii < 4; ++ii) {
        u16 tmp[8];
        #pragma unroll
        for (int e = 0; e < 8; e++) tmp[e] = f2b(acc[ii][e]);
        *(uint4*)(ob + ((size_t)(bl * 64 + i0 + ii) * 64 + j) * 128 + h * 32 + dh) = *(uint4*)tmp;
    }
}

// ---------------------------------------------------------------- final diag head (fp32 out)
__global__ __launch_bounds__(256) void out_kernel(
    const float* __restrict__ tokf, const u16* __restrict__ Wout, const u16* __restrict__ bout,
    float* __restrict__ out)
{
    int g = blockIdx.x * 256 + threadIdx.x;   // [0,512)
    int b = g >> 6, i = g & 63;
    const float* p = tokf + ((size_t)(b * 64 + i) * 64 + i) * 128;
    float s = b2f(bout[0]);
    #pragma unroll
    for (int d = 0; d < 128; d++) s += p[d] * b2f(Wout[d]);
    out[g] = s;
}

// ---------------------------------------------------------------- launch
extern "C" void kernel_launch(void* const* d_in, const int* in_sizes, int n_in,
                              void* d_out, int out_size, void* d_ws, size_t ws_size,
                              hipStream_t stream) {
    const void* mask = d_in[2];
    ParamPtrs pp;
    for (int k = 0; k < NSEG; ++k) pp.p[k] = d_in[k < 2 ? k : k + 1];   // skip mask

    char* ws = (char*)d_ws;
    u16* arena = (u16*)ws;                              // 1,833,488 B
    #define AP(k) ((const u16*)ws + h_seg_off[k])
    int*   mmode = (int*)(ws + 1835008);
    u16*   wsw   = (u16*)(ws + 1867776);                // 78*16384 = 1,277,952 B
    float* tokf  = (float*)(ws + 3145728);              // 16 MB
    u16*   tokb  = (u16*)(ws + 19922944);               //  8 MB
    const size_t base = 28311552;
    const size_t MB = 1048576ULL;

    int NB = 8;
    while (NB > 1 && base + (size_t)NB * 7 * MB > ws_size) NB >>= 1;
    int F = 1;
    while (F < 8 && base + (size_t)(32768 / F) * 1024ULL > ws_size) F <<= 1;

    u16*   qb  = (u16*)(ws + base);                       // NB MB
    u16*   kb  = (u16*)(ws + base + (size_t)NB * MB);     // NB MB
    u16*   v2b = (u16*)(ws + base + (size_t)NB * 2 * MB); // NB MB
    float* v1f = (float*)(ws + base + (size_t)NB * 3 * MB); // 2*NB MB
    u16*   sb  = (u16*)(ws + base + (size_t)NB * 5 * MB);   // 2*NB MB
    u16*   ob  = qb;
    u16*   ffb = qb;

    convert_params<<<1024, 256, 0, stream>>>(pp, arena);
    prep_weights<<<(NTILE * 8192) / 256, 256, 0, stream>>>(arena, wsw);
    probe_kernel<<<1, 256, 0, stream>>>(mask, mmode);
    assemble_kernel<<<4096, 256, 0, stream>>>(AP(0), AP(1), mask, mmode,
                                              AP(2), AP(3), AP(4), AP(5), AP(6), tokf, tokb);

    for (int l = 0; l < 3; ++l) {
        const u16* Bq  = wsw + (size_t)(l * 10 + 0) * 8192;
        const u16* Bk  = wsw + (size_t)(l * 10 + 2) * 8192;
        const u16* Bv1 = wsw + (size_t)(l * 10 + 4) * 8192;
        const u16* Bv2 = wsw + (size_t)(l * 10 + 6) * 8192;
        const u16* Bo  = wsw + (size_t)(l * 10 + 8) * 8192;
        const u16* B1s = wsw + (size_t)(30 + l * 8) * 8192;
        const u16* B2s = wsw + (size_t)(54 + l * 8) * 8192;
        const u16* bo_l  = AP(12) + l * 128;
        const u16* g1_l  = AP(13) + l * 128;
        const u16* be1_l = AP(14) + l * 128;
        const u16* b1_l  = AP(16) + l * 512;
        const u16* b2_l  = AP(18) + l * 128;
        const u16* g2_l  = AP(19) + l * 128;
        const u16* be2_l = AP(20) + l * 128;

        for (int r = 0; r < 8 / NB; ++r) {
            size_t rowOff = (size_t)r * NB * 4096;
            gemm_kernel<<<dim3(NB * 32, 4), 256, 0, stream>>>(
                tokb + rowOff * 128, 128, Bq, Bk, Bv1, Bv2,
                (const u16*)0, 128, 3, (u16*)0, 0, v1f, qb, kb, v2b);
            attn_s_kernel<<<NB * 256, 64, 0, stream>>>(qb, kb, sb);
            softmax_kernel<<<NB * 64, 256, 0, stream>>>(sb);
            attn_o_kernel<<<dim3(NB * 4, 16), 256, 0, stream>>>(sb, v1f, v2b, ob);
            gemm_ln_kernel<<<NB * 32, 256, 0, stream>>>(
                ob, 128, Bo, 128, bo_l, g1_l, be1_l,
                tokf + rowOff * 128, tokb + rowOff * 128);
        }
        for (int f = 0; f < F; ++f) {
            size_t r0 = (size_t)f * (32768 / F);
            int RB = (32768 / F) / 128;
            gemm_kernel<<<dim3(RB, 4), 256, 0, stream>>>(
                tokb + r0 * 128, 128, B1s, (const u16*)0, (const u16*)0, (const u16*)0,
                b1_l, 128, 1, ffb, 512, (float*)0, (u16*)0, (u16*)0, (u16*)0);
            gemm_ln_kernel<<<RB, 256, 0, stream>>>(
                ffb, 512, B2s, 512, b2_l, g2_l, be2_l,
                tokf + r0 * 128, tokb + r0 * 128);
        }
    }
    out_kernel<<<2, 256, 0, stream>>>(tokf, AP(21), AP(22), (float*)d_out);
}